// Round 1
// baseline (772.997 us; speedup 1.0000x reference)
//
#include <hip/hip_runtime.h>

#define N_NODES 100000
#define N_EDGES 1600000
#define IN_DIM  192
#define H1      64
#define H2      32

// ---------------- degree ----------------
__global__ __launch_bounds__(256) void deg_kernel(const int* __restrict__ edges,
                                                  float* __restrict__ deg) {
    int e = blockIdx.x * blockDim.x + threadIdx.x;
    if (e < N_EDGES) {
        int s = edges[2 * e];
        atomicAdd(&deg[s], 1.0f);
    }
}

__global__ __launch_bounds__(256) void dinv_kernel(float* __restrict__ deg) {
    int i = blockIdx.x * blockDim.x + threadIdx.x;
    if (i < N_NODES) {
        float v = deg[i];
        deg[i] = (v > 0.f) ? rsqrtf(v) : 0.f;
    }
}

// ---------------- layer-1 dual GEMM: h = x@W0 + b1, y1 = x@W1 ----------------
// 16 nodes / block, 256 threads (4 waves, 4 nodes each), W staged in LDS chunks.
__global__ __launch_bounds__(256) void gemm1_kernel(
    const float* __restrict__ verts, const float* __restrict__ W0,
    const float* __restrict__ W1, const float* __restrict__ b1,
    float* __restrict__ h, float* __restrict__ y1) {
    __shared__ float xs[16][IN_DIM];     // 12 KB
    __shared__ float w0s[48][H1];        // 12 KB
    __shared__ float w1s[48][H1];        // 12 KB

    int nb = blockIdx.x * 16;
    for (int l = threadIdx.x; l < 16 * IN_DIM; l += 256)
        xs[l / IN_DIM][l % IN_DIM] = verts[(size_t)nb * IN_DIM + l];

    int col = threadIdx.x & 63;
    int w   = threadIdx.x >> 6;
    float acc0[4] = {0.f, 0.f, 0.f, 0.f};
    float acc1[4] = {0.f, 0.f, 0.f, 0.f};

    for (int kc = 0; kc < IN_DIM; kc += 48) {
        __syncthreads();   // covers xs on first iter, w-reuse after
        for (int l = threadIdx.x; l < 48 * H1; l += 256) {
            int kk = l >> 6, cc = l & 63;
            w0s[kk][cc] = W0[(size_t)(kc + kk) * H1 + cc];
            w1s[kk][cc] = W1[(size_t)(kc + kk) * H1 + cc];
        }
        __syncthreads();
        for (int kk = 0; kk < 48; ++kk) {
            float wv0 = w0s[kk][col];
            float wv1 = w1s[kk][col];
#pragma unroll
            for (int j = 0; j < 4; ++j) {
                float xv = xs[w * 4 + j][kc + kk];
                acc0[j] += xv * wv0;
                acc1[j] += xv * wv1;
            }
        }
    }

    float bias = b1[col];
#pragma unroll
    for (int j = 0; j < 4; ++j) {
        int node = nb + w * 4 + j;
        h [(size_t)node * H1 + col] = acc0[j] + bias;
        y1[(size_t)node * H1 + col] = acc1[j];
    }
}

// ---------------- scatter layer 1: h[dst] += norm * y1[src], width 64 ----------------
__global__ __launch_bounds__(256) void scatter1_kernel(
    const int* __restrict__ edges, const float* __restrict__ dinv,
    const float* __restrict__ y1, float* __restrict__ h) {
    const int2* __restrict__ e2 = (const int2*)edges;
    int lane = threadIdx.x & 63;
    int wid  = blockIdx.x * (blockDim.x >> 6) + (threadIdx.x >> 6);
    int nw   = gridDim.x * (blockDim.x >> 6);
    for (int e = wid; e < N_EDGES; e += nw) {
        int2 ed = e2[e];                       // wave-uniform broadcast load
        float nm = -dinv[ed.x] * dinv[ed.y];
        float v  = y1[(size_t)ed.x * H1 + lane];
        atomicAdd(&h[(size_t)ed.y * H1 + lane], nm * v);
    }
}

// ---------------- layer-2 dual GEMM with fused relu-on-load ----------------
// 32 nodes / block, 256 threads; lanes 0..31 -> W0 path (writes out+b2),
// lanes 32..63 -> W1 path (writes y2).
__global__ __launch_bounds__(256) void gemm2_kernel(
    const float* __restrict__ h, const float* __restrict__ W0,
    const float* __restrict__ W1, const float* __restrict__ b2,
    float* __restrict__ out, float* __restrict__ y2) {
    __shared__ float xs[32][H1];        // 8 KB
    __shared__ float ws[2][H1][H2];     // 16 KB

    int nb = blockIdx.x * 32;
    for (int l = threadIdx.x; l < 32 * H1; l += 256) {
        float v = h[(size_t)nb * H1 + l];
        xs[l >> 6][l & 63] = fmaxf(v, 0.f);
    }
    for (int l = threadIdx.x; l < H1 * H2; l += 256) {
        ws[0][l >> 5][l & 31] = W0[l];
        ws[1][l >> 5][l & 31] = W1[l];
    }
    __syncthreads();

    int lane = threadIdx.x & 63;
    int w    = threadIdx.x >> 6;
    int sel  = lane >> 5;            // 0: out path, 1: y2 path
    int col  = lane & 31;
    float acc[8] = {0.f, 0.f, 0.f, 0.f, 0.f, 0.f, 0.f, 0.f};

    for (int k = 0; k < H1; ++k) {
        float wv = ws[sel][k][col];
#pragma unroll
        for (int j = 0; j < 8; ++j)
            acc[j] += xs[w * 8 + j][k] * wv;
    }

    int base = nb + w * 8;
    if (sel == 0) {
        float bias = b2[col];
#pragma unroll
        for (int j = 0; j < 8; ++j)
            out[(size_t)(base + j) * H2 + col] = acc[j] + bias;
    } else {
#pragma unroll
        for (int j = 0; j < 8; ++j)
            y2[(size_t)(base + j) * H2 + col] = acc[j];
    }
}

// ---------------- scatter layer 2: out[dst] += norm * y2[src], width 32 ----------------
// 2 edges per wave (lane>>5 selects edge, lane&31 is the column).
__global__ __launch_bounds__(256) void scatter2_kernel(
    const int* __restrict__ edges, const float* __restrict__ dinv,
    const float* __restrict__ y2, float* __restrict__ out) {
    const int2* __restrict__ e2 = (const int2*)edges;
    int lane = threadIdx.x & 63;
    int sub  = lane >> 5;
    int col  = lane & 31;
    int wid  = blockIdx.x * (blockDim.x >> 6) + (threadIdx.x >> 6);
    int nw   = gridDim.x * (blockDim.x >> 6);
    for (int eb = wid * 2; eb < N_EDGES; eb += nw * 2) {
        int e = eb + sub;
        if (e < N_EDGES) {
            int2 ed = e2[e];
            float nm = -dinv[ed.x] * dinv[ed.y];
            float v  = y2[(size_t)ed.x * H2 + col];
            atomicAdd(&out[(size_t)ed.y * H2 + col], nm * v);
        }
    }
}

extern "C" void kernel_launch(void* const* d_in, const int* in_sizes, int n_in,
                              void* d_out, int out_size, void* d_ws, size_t ws_size,
                              hipStream_t stream) {
    const float* verts = (const float*)d_in[0];
    const int*   edges = (const int*)  d_in[1];
    const float* W0_1  = (const float*)d_in[2];
    const float* W1_1  = (const float*)d_in[3];
    const float* b1    = (const float*)d_in[4];
    const float* W0_2  = (const float*)d_in[5];
    const float* W1_2  = (const float*)d_in[6];
    const float* b2    = (const float*)d_in[7];
    float* out = (float*)d_out;

    // workspace layout (256B-aligned slices)
    char* ws = (char*)d_ws;
    auto align256 = [](size_t x) { return (x + 255) & ~(size_t)255; };
    size_t o_deg = 0;
    size_t o_h   = align256(o_deg + (size_t)N_NODES * 4);
    size_t o_y1  = align256(o_h   + (size_t)N_NODES * H1 * 4);
    size_t o_y2  = align256(o_y1  + (size_t)N_NODES * H1 * 4);
    float* deg = (float*)(ws + o_deg);
    float* h   = (float*)(ws + o_h);
    float* y1  = (float*)(ws + o_y1);
    float* y2  = (float*)(ws + o_y2);

    hipMemsetAsync(deg, 0, (size_t)N_NODES * sizeof(float), stream);
    deg_kernel <<<(N_EDGES + 255) / 256, 256, 0, stream>>>(edges, deg);
    dinv_kernel<<<(N_NODES + 255) / 256, 256, 0, stream>>>(deg);

    gemm1_kernel<<<N_NODES / 16, 256, 0, stream>>>(verts, W0_1, W1_1, b1, h, y1);
    scatter1_kernel<<<4096, 256, 0, stream>>>(edges, deg, y1, h);
    gemm2_kernel<<<N_NODES / 32, 256, 0, stream>>>(h, W0_2, W1_2, b2, out, y2);
    scatter2_kernel<<<4096, 256, 0, stream>>>(edges, deg, y2, out);
}

// Round 2
// 602.224 us; speedup vs baseline: 1.2836x; 1.2836x over previous
//
#include <hip/hip_runtime.h>

#define N_NODES 100000
#define N_EDGES 1600000
#define IN_DIM  192
#define H1      64
#define H2      32
#define NBLK    ((N_NODES + 255) / 256)   // 391 scan blocks

// ---------------- histogram: deg by src (for dinv), cnt by dst (for CSR) ----------------
__global__ __launch_bounds__(256) void hist_kernel(const int* __restrict__ edges,
                                                   int* __restrict__ degi,
                                                   int* __restrict__ cnt) {
    int e = blockIdx.x * blockDim.x + threadIdx.x;
    if (e < N_EDGES) {
        int2 ed = ((const int2*)edges)[e];
        atomicAdd(&degi[ed.x], 1);
        atomicAdd(&cnt[ed.y], 1);
    }
}

__global__ __launch_bounds__(256) void dinv_kernel(const int* __restrict__ degi,
                                                   float* __restrict__ dinv) {
    int i = blockIdx.x * blockDim.x + threadIdx.x;
    if (i < N_NODES) {
        int v = degi[i];
        dinv[i] = (v > 0) ? rsqrtf((float)v) : 0.f;
    }
}

// ---------------- 3-kernel exclusive scan of cnt -> row_start (+ next copy) ----------------
__global__ __launch_bounds__(256) void scanA_kernel(const int* __restrict__ cnt,
                                                    int* __restrict__ excl,
                                                    int* __restrict__ bsum) {
    __shared__ int s[256];
    int i = blockIdx.x * 256 + threadIdx.x;
    int v = (i < N_NODES) ? cnt[i] : 0;
    s[threadIdx.x] = v;
    __syncthreads();
    for (int off = 1; off < 256; off <<= 1) {
        int t = (threadIdx.x >= off) ? s[threadIdx.x - off] : 0;
        __syncthreads();
        s[threadIdx.x] += t;
        __syncthreads();
    }
    if (i < N_NODES) excl[i] = s[threadIdx.x] - v;   // exclusive
    if (threadIdx.x == 255) bsum[blockIdx.x] = s[255];
}

__global__ __launch_bounds__(512) void scanB_kernel(int* __restrict__ bsum) {
    __shared__ int s[512];
    int v = (threadIdx.x < NBLK) ? bsum[threadIdx.x] : 0;
    s[threadIdx.x] = v;
    __syncthreads();
    for (int off = 1; off < 512; off <<= 1) {
        int t = (threadIdx.x >= off) ? s[threadIdx.x - off] : 0;
        __syncthreads();
        s[threadIdx.x] += t;
        __syncthreads();
    }
    if (threadIdx.x < NBLK) bsum[threadIdx.x] = s[threadIdx.x] - v;  // exclusive
}

__global__ __launch_bounds__(256) void scanC_kernel(const int* __restrict__ excl,
                                                    const int* __restrict__ bsum,
                                                    int* __restrict__ row_start,
                                                    int* __restrict__ next) {
    int i = blockIdx.x * 256 + threadIdx.x;
    if (i < N_NODES) {
        int r = excl[i] + bsum[blockIdx.x];
        row_start[i] = r;
        next[i] = r;
    }
}

// ---------------- CSR fill: col[pos] = src, sorted by dst ----------------
__global__ __launch_bounds__(256) void fill_kernel(const int* __restrict__ edges,
                                                   int* __restrict__ next,
                                                   int* __restrict__ col) {
    int e = blockIdx.x * blockDim.x + threadIdx.x;
    if (e < N_EDGES) {
        int2 ed = ((const int2*)edges)[e];
        int pos = atomicAdd(&next[ed.y], 1);
        col[pos] = ed.x;
    }
}

// ---------------- layer-1 dual GEMM: h = x@W0 + b1, y1 = x@W1 ----------------
__global__ __launch_bounds__(256) void gemm1_kernel(
    const float* __restrict__ verts, const float* __restrict__ W0,
    const float* __restrict__ W1, const float* __restrict__ b1,
    float* __restrict__ h, float* __restrict__ y1) {
    __shared__ float xs[16][IN_DIM];
    __shared__ float w0s[48][H1];
    __shared__ float w1s[48][H1];

    int nb = blockIdx.x * 16;
    for (int l = threadIdx.x; l < 16 * IN_DIM; l += 256)
        xs[l / IN_DIM][l % IN_DIM] = verts[(size_t)nb * IN_DIM + l];

    int col = threadIdx.x & 63;
    int w   = threadIdx.x >> 6;
    float acc0[4] = {0.f, 0.f, 0.f, 0.f};
    float acc1[4] = {0.f, 0.f, 0.f, 0.f};

    for (int kc = 0; kc < IN_DIM; kc += 48) {
        __syncthreads();
        for (int l = threadIdx.x; l < 48 * H1; l += 256) {
            int kk = l >> 6, cc = l & 63;
            w0s[kk][cc] = W0[(size_t)(kc + kk) * H1 + cc];
            w1s[kk][cc] = W1[(size_t)(kc + kk) * H1 + cc];
        }
        __syncthreads();
        for (int kk = 0; kk < 48; ++kk) {
            float wv0 = w0s[kk][col];
            float wv1 = w1s[kk][col];
#pragma unroll
            for (int j = 0; j < 4; ++j) {
                float xv = xs[w * 4 + j][kc + kk];
                acc0[j] += xv * wv0;
                acc1[j] += xv * wv1;
            }
        }
    }

    float bias = b1[col];
#pragma unroll
    for (int j = 0; j < 4; ++j) {
        int node = nb + w * 4 + j;
        h [(size_t)node * H1 + col] = acc0[j] + bias;
        y1[(size_t)node * H1 + col] = acc1[j];
    }
}

// ---------------- gather layer 1: h[n] -= dinv[n] * sum(dinv[src]*y1[src]) ----------------
// one wave per node, lane = channel
__global__ __launch_bounds__(256) void gather1_kernel(
    const int* __restrict__ row_start, const int* __restrict__ cnt,
    const int* __restrict__ col, const float* __restrict__ dinv,
    const float* __restrict__ y1, float* __restrict__ h) {
    int n = blockIdx.x * 4 + (threadIdx.x >> 6);
    if (n >= N_NODES) return;
    int lane = threadIdx.x & 63;
    int beg = row_start[n], c = cnt[n];
    float acc = 0.f;
    int i = 0;
    for (; i + 1 < c; i += 2) {
        int s0 = col[beg + i], s1 = col[beg + i + 1];
        float w0 = dinv[s0], w1 = dinv[s1];
        float v0 = y1[(size_t)s0 * H1 + lane];
        float v1 = y1[(size_t)s1 * H1 + lane];
        acc += w0 * v0 + w1 * v1;
    }
    if (i < c) {
        int s0 = col[beg + i];
        acc += dinv[s0] * y1[(size_t)s0 * H1 + lane];
    }
    size_t idx = (size_t)n * H1 + lane;
    h[idx] = h[idx] - dinv[n] * acc;
}

// ---------------- layer-2 dual GEMM with fused relu-on-load ----------------
__global__ __launch_bounds__(256) void gemm2_kernel(
    const float* __restrict__ h, const float* __restrict__ W0,
    const float* __restrict__ W1, const float* __restrict__ b2,
    float* __restrict__ out, float* __restrict__ y2) {
    __shared__ float xs[32][H1];
    __shared__ float ws[2][H1][H2];

    int nb = blockIdx.x * 32;
    for (int l = threadIdx.x; l < 32 * H1; l += 256) {
        float v = h[(size_t)nb * H1 + l];
        xs[l >> 6][l & 63] = fmaxf(v, 0.f);
    }
    for (int l = threadIdx.x; l < H1 * H2; l += 256) {
        ws[0][l >> 5][l & 31] = W0[l];
        ws[1][l >> 5][l & 31] = W1[l];
    }
    __syncthreads();

    int lane = threadIdx.x & 63;
    int w    = threadIdx.x >> 6;
    int sel  = lane >> 5;
    int col  = lane & 31;
    float acc[8] = {0.f, 0.f, 0.f, 0.f, 0.f, 0.f, 0.f, 0.f};

    for (int k = 0; k < H1; ++k) {
        float wv = ws[sel][k][col];
#pragma unroll
        for (int j = 0; j < 8; ++j)
            acc[j] += xs[w * 8 + j][k] * wv;
    }

    int base = nb + w * 8;
    if (sel == 0) {
        float bias = b2[col];
#pragma unroll
        for (int j = 0; j < 8; ++j)
            out[(size_t)(base + j) * H2 + col] = acc[j] + bias;
    } else {
#pragma unroll
        for (int j = 0; j < 8; ++j)
            y2[(size_t)(base + j) * H2 + col] = acc[j];
    }
}

// ---------------- gather layer 2: out[n] -= dinv[n] * sum(dinv[src]*y2[src]) ----------------
// 2 nodes per wave (lane>>5 selects node, lane&31 is the column)
__global__ __launch_bounds__(256) void gather2_kernel(
    const int* __restrict__ row_start, const int* __restrict__ cnt,
    const int* __restrict__ col, const float* __restrict__ dinv,
    const float* __restrict__ y2, float* __restrict__ out) {
    int wave = (blockIdx.x * 256 + threadIdx.x) >> 6;
    int lane = threadIdx.x & 63;
    int n = wave * 2 + (lane >> 5);
    if (n >= N_NODES) return;
    int c32 = lane & 31;
    int beg = row_start[n], c = cnt[n];
    float acc = 0.f;
    int i = 0;
    for (; i + 1 < c; i += 2) {
        int s0 = col[beg + i], s1 = col[beg + i + 1];
        float w0 = dinv[s0], w1 = dinv[s1];
        float v0 = y2[(size_t)s0 * H2 + c32];
        float v1 = y2[(size_t)s1 * H2 + c32];
        acc += w0 * v0 + w1 * v1;
    }
    if (i < c) {
        int s0 = col[beg + i];
        acc += dinv[s0] * y2[(size_t)s0 * H2 + c32];
    }
    size_t idx = (size_t)n * H2 + c32;
    out[idx] = out[idx] - dinv[n] * acc;
}

extern "C" void kernel_launch(void* const* d_in, const int* in_sizes, int n_in,
                              void* d_out, int out_size, void* d_ws, size_t ws_size,
                              hipStream_t stream) {
    const float* verts = (const float*)d_in[0];
    const int*   edges = (const int*)  d_in[1];
    const float* W0_1  = (const float*)d_in[2];
    const float* W1_1  = (const float*)d_in[3];
    const float* b1    = (const float*)d_in[4];
    const float* W0_2  = (const float*)d_in[5];
    const float* W1_2  = (const float*)d_in[6];
    const float* b2    = (const float*)d_in[7];
    float* out = (float*)d_out;

    char* ws = (char*)d_ws;
    auto align256 = [](size_t x) { return (x + 255) & ~(size_t)255; };
    size_t o = 0;
    auto alloc = [&](size_t bytes) { size_t r = o; o = align256(o + bytes); return r; };

    int*   degi      = (int*)  (ws + alloc((size_t)N_NODES * 4));
    int*   cnt       = (int*)  (ws + alloc((size_t)N_NODES * 4));
    float* dinv      = (float*)(ws + alloc((size_t)N_NODES * 4));
    int*   excl      = (int*)  (ws + alloc((size_t)N_NODES * 4));
    int*   bsum      = (int*)  (ws + alloc((size_t)NBLK * 4));
    int*   row_start = (int*)  (ws + alloc((size_t)N_NODES * 4));
    int*   nextp     = (int*)  (ws + alloc((size_t)N_NODES * 4));
    int*   colarr    = (int*)  (ws + alloc((size_t)N_EDGES * 4));
    float* h         = (float*)(ws + alloc((size_t)N_NODES * H1 * 4));
    float* y1        = (float*)(ws + alloc((size_t)N_NODES * H1 * 4));
    float* y2        = (float*)(ws + alloc((size_t)N_NODES * H2 * 4));

    // degi and cnt are adjacent at the front: one memset covers both
    hipMemsetAsync(degi, 0, align256((size_t)N_NODES * 4) + (size_t)N_NODES * 4, stream);

    hist_kernel <<<(N_EDGES + 255) / 256, 256, 0, stream>>>(edges, degi, cnt);
    dinv_kernel <<<NBLK, 256, 0, stream>>>(degi, dinv);
    scanA_kernel<<<NBLK, 256, 0, stream>>>(cnt, excl, bsum);
    scanB_kernel<<<1, 512, 0, stream>>>(bsum);
    scanC_kernel<<<NBLK, 256, 0, stream>>>(excl, bsum, row_start, nextp);
    fill_kernel <<<(N_EDGES + 255) / 256, 256, 0, stream>>>(edges, nextp, colarr);

    gemm1_kernel  <<<N_NODES / 16, 256, 0, stream>>>(verts, W0_1, W1_1, b1, h, y1);
    gather1_kernel<<<(N_NODES + 3) / 4, 256, 0, stream>>>(row_start, cnt, colarr, dinv, y1, h);
    gemm2_kernel  <<<N_NODES / 32, 256, 0, stream>>>(h, W0_2, W1_2, b2, out, y2);
    gather2_kernel<<<(N_NODES + 7) / 8, 256, 0, stream>>>(row_start, cnt, colarr, dinv, y2, out);
}

// Round 3
// 468.404 us; speedup vs baseline: 1.6503x; 1.2857x over previous
//
#include <hip/hip_runtime.h>

#define N_NODES 100000
#define N_EDGES 1600000
#define IN_DIM  192
#define H1      64
#define H2      32
#define NBLK    ((N_NODES + 255) / 256)   // 391 scan blocks

typedef __attribute__((ext_vector_type(8))) short short8;
typedef __attribute__((ext_vector_type(4))) float f32x4;

__device__ inline short f2bf(float f) {
    union { float f; unsigned u; } v; v.f = f;
    unsigned r = (v.u + 0x7FFFu + ((v.u >> 16) & 1u)) >> 16;
    return (short)r;
}
__device__ inline float bf2f(unsigned short s) {
    union { unsigned u; float f; } v; v.u = ((unsigned)s) << 16;
    return v.f;
}

// ---------------- histogram: deg by src (for dinv), cnt by dst (for CSR) ----------------
__global__ __launch_bounds__(256) void hist_kernel(const int* __restrict__ edges,
                                                   int* __restrict__ degi,
                                                   int* __restrict__ cnt) {
    int e = blockIdx.x * blockDim.x + threadIdx.x;
    if (e < N_EDGES) {
        int2 ed = ((const int2*)edges)[e];
        atomicAdd(&degi[ed.x], 1);
        atomicAdd(&cnt[ed.y], 1);
    }
}

__global__ __launch_bounds__(256) void dinv_kernel(const int* __restrict__ degi,
                                                   float* __restrict__ dinv) {
    int i = blockIdx.x * blockDim.x + threadIdx.x;
    if (i < N_NODES) {
        int v = degi[i];
        dinv[i] = (v > 0) ? rsqrtf((float)v) : 0.f;
    }
}

// ---------------- 3-kernel exclusive scan of cnt -> row_start (+ next copy) ----------------
__global__ __launch_bounds__(256) void scanA_kernel(const int* __restrict__ cnt,
                                                    int* __restrict__ excl,
                                                    int* __restrict__ bsum) {
    __shared__ int s[256];
    int i = blockIdx.x * 256 + threadIdx.x;
    int v = (i < N_NODES) ? cnt[i] : 0;
    s[threadIdx.x] = v;
    __syncthreads();
    for (int off = 1; off < 256; off <<= 1) {
        int t = (threadIdx.x >= off) ? s[threadIdx.x - off] : 0;
        __syncthreads();
        s[threadIdx.x] += t;
        __syncthreads();
    }
    if (i < N_NODES) excl[i] = s[threadIdx.x] - v;
    if (threadIdx.x == 255) bsum[blockIdx.x] = s[255];
}

__global__ __launch_bounds__(512) void scanB_kernel(int* __restrict__ bsum) {
    __shared__ int s[512];
    int v = (threadIdx.x < NBLK) ? bsum[threadIdx.x] : 0;
    s[threadIdx.x] = v;
    __syncthreads();
    for (int off = 1; off < 512; off <<= 1) {
        int t = (threadIdx.x >= off) ? s[threadIdx.x - off] : 0;
        __syncthreads();
        s[threadIdx.x] += t;
        __syncthreads();
    }
    if (threadIdx.x < NBLK) bsum[threadIdx.x] = s[threadIdx.x] - v;
}

__global__ __launch_bounds__(256) void scanC_kernel(const int* __restrict__ excl,
                                                    const int* __restrict__ bsum,
                                                    int* __restrict__ row_start,
                                                    int* __restrict__ next) {
    int i = blockIdx.x * 256 + threadIdx.x;
    if (i < N_NODES) {
        int r = excl[i] + bsum[blockIdx.x];
        row_start[i] = r;
        next[i] = r;
    }
}

// ---------------- CSR fill: col[pos] = src, sorted by dst ----------------
__global__ __launch_bounds__(256) void fill_kernel(const int* __restrict__ edges,
                                                   int* __restrict__ next,
                                                   int* __restrict__ col) {
    int e = blockIdx.x * blockDim.x + threadIdx.x;
    if (e < N_EDGES) {
        int2 ed = ((const int2*)edges)[e];
        int pos = atomicAdd(&next[ed.y], 1);
        col[pos] = ed.x;
    }
}

// ---------------- weight prep: Bt1[128][192], Bt2[64][64], bf16, N-major (transposed) ----
__global__ __launch_bounds__(256) void prep_w_kernel(
    const float* __restrict__ W0_1, const float* __restrict__ W1_1,
    const float* __restrict__ W0_2, const float* __restrict__ W1_2,
    short* __restrict__ Bt1, short* __restrict__ Bt2) {
    int idx = blockIdx.x * 256 + threadIdx.x;
    if (idx < 128 * IN_DIM) {
        int n = idx / IN_DIM, k = idx % IN_DIM;
        float v = (n < H1) ? W0_1[(size_t)k * H1 + n] : W1_1[(size_t)k * H1 + (n - H1)];
        Bt1[idx] = f2bf(v);
    } else {
        int j = idx - 128 * IN_DIM;
        if (j < 64 * H1) {
            int n = j / H1, k = j % H1;
            float v = (n < H2) ? W0_2[(size_t)k * H2 + n] : W1_2[(size_t)k * H2 + (n - H2)];
            Bt2[j] = f2bf(v);
        }
    }
}

// ---------------- layer-1 MFMA GEMM: [h | y1b] = verts @ [W0_1 | W1_1] ----------------
// block = 4 waves, 32 rows/wave (2 M-frags), N=128 (8 col-frags), K=192 (6 k-steps).
// A loaded fp32 from global (L3-resident), converted inline; B from L2-resident Bt1.
__global__ __launch_bounds__(256) void gemm1_mfma(
    const float* __restrict__ verts, const short* __restrict__ Bt1,
    const float* __restrict__ b1, float* __restrict__ h, short* __restrict__ y1b) {
    int lane = threadIdx.x & 63;
    int wave = threadIdx.x >> 6;
    int rowbase = blockIdx.x * 128 + wave * 32;
    int lr = lane & 15;              // row/col within fragment
    int lk = (lane >> 4) * 8;        // k-subgroup base

    short8 a[2][6];
#pragma unroll
    for (int mr = 0; mr < 2; ++mr) {
        int row = rowbase + mr * 16 + lr;
        int rc = (row < N_NODES) ? row : (N_NODES - 1);
        const float* p = verts + (size_t)rc * IN_DIM + lk;
#pragma unroll
        for (int ks = 0; ks < 6; ++ks) {
            f32x4 u0 = *(const f32x4*)(p + ks * 32);
            f32x4 u1 = *(const f32x4*)(p + ks * 32 + 4);
            short8 t;
            t[0] = f2bf(u0[0]); t[1] = f2bf(u0[1]); t[2] = f2bf(u0[2]); t[3] = f2bf(u0[3]);
            t[4] = f2bf(u1[0]); t[5] = f2bf(u1[1]); t[6] = f2bf(u1[2]); t[7] = f2bf(u1[3]);
            a[mr][ks] = t;
        }
    }

    f32x4 acc[2][8] = {};
#pragma unroll
    for (int cf = 0; cf < 8; ++cf) {
        const short* bp = Bt1 + (size_t)(cf * 16 + lr) * IN_DIM + lk;
#pragma unroll
        for (int ks = 0; ks < 6; ++ks) {
            short8 b = *(const short8*)(bp + ks * 32);
            acc[0][cf] = __builtin_amdgcn_mfma_f32_16x16x32_bf16(a[0][ks], b, acc[0][cf], 0, 0, 0);
            acc[1][cf] = __builtin_amdgcn_mfma_f32_16x16x32_bf16(a[1][ks], b, acc[1][cf], 0, 0, 0);
        }
    }

    int srow = (lane >> 4) * 4;
#pragma unroll
    for (int mr = 0; mr < 2; ++mr) {
#pragma unroll
        for (int cf = 0; cf < 8; ++cf) {
            int colc = cf * 16 + lr;
            float bias = (colc < H1) ? b1[colc] : 0.f;
#pragma unroll
            for (int r = 0; r < 4; ++r) {
                int row = rowbase + mr * 16 + srow + r;
                if (row < N_NODES) {
                    float v = acc[mr][cf][r];
                    if (colc < H1) h[(size_t)row * H1 + colc] = v + bias;
                    else           y1b[(size_t)row * H1 + (colc - H1)] = f2bf(v);
                }
            }
        }
    }
}

// ---------------- gather layer 1 + fused relu/bf16: hb = bf16(relu(h - dinv*sum)) --------
__global__ __launch_bounds__(256) void gather1_kernel(
    const int* __restrict__ row_start, const int* __restrict__ cnt,
    const int* __restrict__ col, const float* __restrict__ dinv,
    const float* __restrict__ h, const unsigned short* __restrict__ y1b,
    short* __restrict__ hb) {
    int n = blockIdx.x * 4 + (threadIdx.x >> 6);
    if (n >= N_NODES) return;
    int lane = threadIdx.x & 63;
    int beg = row_start[n], c = cnt[n];
    float acc = 0.f;
    int i = 0;
    for (; i + 1 < c; i += 2) {
        int s0 = col[beg + i], s1 = col[beg + i + 1];
        float w0 = dinv[s0], w1 = dinv[s1];
        float v0 = bf2f(y1b[(size_t)s0 * H1 + lane]);
        float v1 = bf2f(y1b[(size_t)s1 * H1 + lane]);
        acc += w0 * v0 + w1 * v1;
    }
    if (i < c) {
        int s0 = col[beg + i];
        acc += dinv[s0] * bf2f(y1b[(size_t)s0 * H1 + lane]);
    }
    size_t idx = (size_t)n * H1 + lane;
    float hf = h[idx] - dinv[n] * acc;
    hb[idx] = f2bf(fmaxf(hf, 0.f));
}

// ---------------- layer-2 MFMA GEMM: [out | y2b] = relu(h) @ [W0_2 | W1_2] ----------------
// 32 rows/wave, N=64 (4 col-frags), K=64 (2 k-steps). A is hb (bf16), direct loads.
__global__ __launch_bounds__(256) void gemm2_mfma(
    const short* __restrict__ hb, const short* __restrict__ Bt2,
    const float* __restrict__ b2, float* __restrict__ out, short* __restrict__ y2b) {
    int lane = threadIdx.x & 63;
    int wave = threadIdx.x >> 6;
    int rowbase = blockIdx.x * 128 + wave * 32;
    int lr = lane & 15;
    int lk = (lane >> 4) * 8;

    short8 a[2][2];
#pragma unroll
    for (int mr = 0; mr < 2; ++mr) {
        int row = rowbase + mr * 16 + lr;
        int rc = (row < N_NODES) ? row : (N_NODES - 1);
        const short* p = hb + (size_t)rc * H1 + lk;
        a[mr][0] = *(const short8*)(p);
        a[mr][1] = *(const short8*)(p + 32);
    }

    f32x4 acc[2][4] = {};
#pragma unroll
    for (int cf = 0; cf < 4; ++cf) {
        const short* bp = Bt2 + (size_t)(cf * 16 + lr) * H1 + lk;
#pragma unroll
        for (int ks = 0; ks < 2; ++ks) {
            short8 b = *(const short8*)(bp + ks * 32);
            acc[0][cf] = __builtin_amdgcn_mfma_f32_16x16x32_bf16(a[0][ks], b, acc[0][cf], 0, 0, 0);
            acc[1][cf] = __builtin_amdgcn_mfma_f32_16x16x32_bf16(a[1][ks], b, acc[1][cf], 0, 0, 0);
        }
    }

    int srow = (lane >> 4) * 4;
#pragma unroll
    for (int mr = 0; mr < 2; ++mr) {
#pragma unroll
        for (int cf = 0; cf < 4; ++cf) {
            int colc = cf * 16 + lr;
            float bias = (colc < H2) ? b2[colc] : 0.f;
#pragma unroll
            for (int r = 0; r < 4; ++r) {
                int row = rowbase + mr * 16 + srow + r;
                if (row < N_NODES) {
                    float v = acc[mr][cf][r];
                    if (colc < H2) out[(size_t)row * H2 + colc] = v + bias;
                    else           y2b[(size_t)row * H2 + (colc - H2)] = f2bf(v);
                }
            }
        }
    }
}

// ---------------- gather layer 2: out[n] -= dinv[n] * sum(dinv[src]*y2[src]) -------------
__global__ __launch_bounds__(256) void gather2_kernel(
    const int* __restrict__ row_start, const int* __restrict__ cnt,
    const int* __restrict__ col, const float* __restrict__ dinv,
    const unsigned short* __restrict__ y2b, float* __restrict__ out) {
    int wave = (blockIdx.x * 256 + threadIdx.x) >> 6;
    int lane = threadIdx.x & 63;
    int n = wave * 2 + (lane >> 5);
    if (n >= N_NODES) return;
    int c32 = lane & 31;
    int beg = row_start[n], c = cnt[n];
    float acc = 0.f;
    int i = 0;
    for (; i + 1 < c; i += 2) {
        int s0 = col[beg + i], s1 = col[beg + i + 1];
        float w0 = dinv[s0], w1 = dinv[s1];
        float v0 = bf2f(y2b[(size_t)s0 * H2 + c32]);
        float v1 = bf2f(y2b[(size_t)s1 * H2 + c32]);
        acc += w0 * v0 + w1 * v1;
    }
    if (i < c) {
        int s0 = col[beg + i];
        acc += dinv[s0] * bf2f(y2b[(size_t)s0 * H2 + c32]);
    }
    size_t idx = (size_t)n * H2 + c32;
    out[idx] = out[idx] - dinv[n] * acc;
}

extern "C" void kernel_launch(void* const* d_in, const int* in_sizes, int n_in,
                              void* d_out, int out_size, void* d_ws, size_t ws_size,
                              hipStream_t stream) {
    const float* verts = (const float*)d_in[0];
    const int*   edges = (const int*)  d_in[1];
    const float* W0_1  = (const float*)d_in[2];
    const float* W1_1  = (const float*)d_in[3];
    const float* b1    = (const float*)d_in[4];
    const float* W0_2  = (const float*)d_in[5];
    const float* W1_2  = (const float*)d_in[6];
    const float* b2    = (const float*)d_in[7];
    float* out = (float*)d_out;

    char* ws = (char*)d_ws;
    auto align256 = [](size_t x) { return (x + 255) & ~(size_t)255; };
    size_t o = 0;
    auto alloc = [&](size_t bytes) { size_t r = o; o = align256(o + bytes); return r; };

    int*   degi      = (int*)  (ws + alloc((size_t)N_NODES * 4));
    int*   cnt       = (int*)  (ws + alloc((size_t)N_NODES * 4));
    float* dinv      = (float*)(ws + alloc((size_t)N_NODES * 4));
    int*   excl      = (int*)  (ws + alloc((size_t)N_NODES * 4));
    int*   bsum      = (int*)  (ws + alloc((size_t)NBLK * 4));
    int*   row_start = (int*)  (ws + alloc((size_t)N_NODES * 4));
    int*   nextp     = (int*)  (ws + alloc((size_t)N_NODES * 4));
    int*   colarr    = (int*)  (ws + alloc((size_t)N_EDGES * 4));
    short* Bt1       = (short*)(ws + alloc((size_t)128 * IN_DIM * 2));
    short* Bt2       = (short*)(ws + alloc((size_t)64 * H1 * 2));
    float* h         = (float*)(ws + alloc((size_t)N_NODES * H1 * 4));
    short* y1b       = (short*)(ws + alloc((size_t)N_NODES * H1 * 2));
    short* hb        = (short*)(ws + alloc((size_t)N_NODES * H1 * 2));
    short* y2b       = (short*)(ws + alloc((size_t)N_NODES * H2 * 2));

    hipMemsetAsync(degi, 0, align256((size_t)N_NODES * 4) + (size_t)N_NODES * 4, stream);

    hist_kernel  <<<(N_EDGES + 255) / 256, 256, 0, stream>>>(edges, degi, cnt);
    dinv_kernel  <<<NBLK, 256, 0, stream>>>(degi, dinv);
    scanA_kernel <<<NBLK, 256, 0, stream>>>(cnt, excl, bsum);
    scanB_kernel <<<1, 512, 0, stream>>>(bsum);
    scanC_kernel <<<NBLK, 256, 0, stream>>>(excl, bsum, row_start, nextp);
    fill_kernel  <<<(N_EDGES + 255) / 256, 256, 0, stream>>>(edges, nextp, colarr);
    prep_w_kernel<<<(128 * IN_DIM + 64 * H1 + 255) / 256, 256, 0, stream>>>(W0_1, W1_1, W0_2, W1_2, Bt1, Bt2);

    gemm1_mfma    <<<(N_NODES + 127) / 128, 256, 0, stream>>>(verts, Bt1, b1, h, y1b);
    gather1_kernel<<<(N_NODES + 3) / 4, 256, 0, stream>>>(row_start, cnt, colarr, dinv, h, (const unsigned short*)y1b, hb);
    gemm2_mfma    <<<(N_NODES + 127) / 128, 256, 0, stream>>>(hb, Bt2, b2, out, y2b);
    gather2_kernel<<<(N_NODES + 7) / 8, 256, 0, stream>>>(row_start, cnt, colarr, dinv, (const unsigned short*)y2b, out);
}

// Round 4
// 388.582 us; speedup vs baseline: 1.9893x; 1.2054x over previous
//
#include <hip/hip_runtime.h>

#define N_NODES 100000
#define N_EDGES 1600000
#define IN_DIM  192
#define H1      64
#define H2      32
#define NBLK    ((N_NODES + 255) / 256)   // 391 scan blocks

typedef __attribute__((ext_vector_type(8))) short short8;
typedef __attribute__((ext_vector_type(4))) float f32x4;

__device__ inline short f2bf(float f) {
    union { float f; unsigned u; } v; v.f = f;
    unsigned r = (v.u + 0x7FFFu + ((v.u >> 16) & 1u)) >> 16;
    return (short)r;
}
__device__ inline float bf2f(unsigned short s) {
    union { unsigned u; float f; } v; v.u = ((unsigned)s) << 16;
    return v.f;
}

// ------- histogram: deg by src (for dinv), cnt by dst (for CSR) + per-edge rank -------
__global__ __launch_bounds__(256) void hist_kernel(const int* __restrict__ edges,
                                                   int* __restrict__ degi,
                                                   int* __restrict__ cnt,
                                                   int* __restrict__ rank) {
    int e = blockIdx.x * blockDim.x + threadIdx.x;
    if (e < N_EDGES) {
        int2 ed = ((const int2*)edges)[e];
        atomicAdd(&degi[ed.x], 1);
        rank[e] = atomicAdd(&cnt[ed.y], 1);
    }
}

__global__ __launch_bounds__(256) void dinv_kernel(const int* __restrict__ degi,
                                                   float* __restrict__ dinv) {
    int i = blockIdx.x * blockDim.x + threadIdx.x;
    if (i < N_NODES) {
        int v = degi[i];
        dinv[i] = (v > 0) ? rsqrtf((float)v) : 0.f;
    }
}

// ---------------- 3-kernel exclusive scan of cnt -> row_start ----------------
__global__ __launch_bounds__(256) void scanA_kernel(const int* __restrict__ cnt,
                                                    int* __restrict__ excl,
                                                    int* __restrict__ bsum) {
    __shared__ int s[256];
    int i = blockIdx.x * 256 + threadIdx.x;
    int v = (i < N_NODES) ? cnt[i] : 0;
    s[threadIdx.x] = v;
    __syncthreads();
    for (int off = 1; off < 256; off <<= 1) {
        int t = (threadIdx.x >= off) ? s[threadIdx.x - off] : 0;
        __syncthreads();
        s[threadIdx.x] += t;
        __syncthreads();
    }
    if (i < N_NODES) excl[i] = s[threadIdx.x] - v;
    if (threadIdx.x == 255) bsum[blockIdx.x] = s[255];
}

__global__ __launch_bounds__(512) void scanB_kernel(int* __restrict__ bsum) {
    __shared__ int s[512];
    int v = (threadIdx.x < NBLK) ? bsum[threadIdx.x] : 0;
    s[threadIdx.x] = v;
    __syncthreads();
    for (int off = 1; off < 512; off <<= 1) {
        int t = (threadIdx.x >= off) ? s[threadIdx.x - off] : 0;
        __syncthreads();
        s[threadIdx.x] += t;
        __syncthreads();
    }
    if (threadIdx.x < NBLK) bsum[threadIdx.x] = s[threadIdx.x] - v;
}

__global__ __launch_bounds__(256) void scanC_kernel(const int* __restrict__ excl,
                                                    const int* __restrict__ bsum,
                                                    int* __restrict__ row_start) {
    int i = blockIdx.x * 256 + threadIdx.x;
    if (i < N_NODES)
        row_start[i] = excl[i] + bsum[blockIdx.x];
}

// ------- CSR fill, atomic-free: col[row_start[dst] + rank[e]] = src -------
__global__ __launch_bounds__(256) void fill_kernel(const int* __restrict__ edges,
                                                   const int* __restrict__ rank,
                                                   const int* __restrict__ row_start,
                                                   int* __restrict__ col) {
    int e = blockIdx.x * blockDim.x + threadIdx.x;
    if (e < N_EDGES) {
        int2 ed = ((const int2*)edges)[e];
        col[row_start[ed.y] + rank[e]] = ed.x;
    }
}

// ---------------- weight prep: Bt1[128][192], Bt2[64][64], bf16, N-major ----------------
__global__ __launch_bounds__(256) void prep_w_kernel(
    const float* __restrict__ W0_1, const float* __restrict__ W1_1,
    const float* __restrict__ W0_2, const float* __restrict__ W1_2,
    short* __restrict__ Bt1, short* __restrict__ Bt2) {
    int idx = blockIdx.x * 256 + threadIdx.x;
    if (idx < 128 * IN_DIM) {
        int n = idx / IN_DIM, k = idx % IN_DIM;
        float v = (n < H1) ? W0_1[(size_t)k * H1 + n] : W1_1[(size_t)k * H1 + (n - H1)];
        Bt1[idx] = f2bf(v);
    } else {
        int j = idx - 128 * IN_DIM;
        if (j < 64 * H1) {
            int n = j / H1, k = j % H1;
            float v = (n < H2) ? W0_2[(size_t)k * H2 + n] : W1_2[(size_t)k * H2 + (n - H2)];
            Bt2[j] = f2bf(v);
        }
    }
}

// ---------------- layer-1 MFMA GEMM: [h | y1b] = verts @ [W0_1 | W1_1] ----------------
__global__ __launch_bounds__(256) void gemm1_mfma(
    const float* __restrict__ verts, const short* __restrict__ Bt1,
    const float* __restrict__ b1, float* __restrict__ h, short* __restrict__ y1b) {
    int lane = threadIdx.x & 63;
    int wave = threadIdx.x >> 6;
    int rowbase = blockIdx.x * 128 + wave * 32;
    int lr = lane & 15;
    int lk = (lane >> 4) * 8;

    short8 a[2][6];
#pragma unroll
    for (int mr = 0; mr < 2; ++mr) {
        int row = rowbase + mr * 16 + lr;
        int rc = (row < N_NODES) ? row : (N_NODES - 1);
        const float* p = verts + (size_t)rc * IN_DIM + lk;
#pragma unroll
        for (int ks = 0; ks < 6; ++ks) {
            f32x4 u0 = *(const f32x4*)(p + ks * 32);
            f32x4 u1 = *(const f32x4*)(p + ks * 32 + 4);
            short8 t;
            t[0] = f2bf(u0[0]); t[1] = f2bf(u0[1]); t[2] = f2bf(u0[2]); t[3] = f2bf(u0[3]);
            t[4] = f2bf(u1[0]); t[5] = f2bf(u1[1]); t[6] = f2bf(u1[2]); t[7] = f2bf(u1[3]);
            a[mr][ks] = t;
        }
    }

    f32x4 acc[2][8] = {};
#pragma unroll
    for (int cf = 0; cf < 8; ++cf) {
        const short* bp = Bt1 + (size_t)(cf * 16 + lr) * IN_DIM + lk;
#pragma unroll
        for (int ks = 0; ks < 6; ++ks) {
            short8 b = *(const short8*)(bp + ks * 32);
            acc[0][cf] = __builtin_amdgcn_mfma_f32_16x16x32_bf16(a[0][ks], b, acc[0][cf], 0, 0, 0);
            acc[1][cf] = __builtin_amdgcn_mfma_f32_16x16x32_bf16(a[1][ks], b, acc[1][cf], 0, 0, 0);
        }
    }

    int srow = (lane >> 4) * 4;
#pragma unroll
    for (int mr = 0; mr < 2; ++mr) {
#pragma unroll
        for (int cf = 0; cf < 8; ++cf) {
            int colc = cf * 16 + lr;
            float bias = (colc < H1) ? b1[colc] : 0.f;
#pragma unroll
            for (int r = 0; r < 4; ++r) {
                int row = rowbase + mr * 16 + srow + r;
                if (row < N_NODES) {
                    float v = acc[mr][cf][r];
                    if (colc < H1) h[(size_t)row * H1 + colc] = v + bias;
                    else           y1b[(size_t)row * H1 + (colc - H1)] = f2bf(v);
                }
            }
        }
    }
}

// ------- gather layer 1 + fused relu/bf16: hb = bf16(relu(h - dinv*sum)) -------
__global__ __launch_bounds__(256) void gather1_kernel(
    const int* __restrict__ row_start, const int* __restrict__ cnt,
    const int* __restrict__ col, const float* __restrict__ dinv,
    const float* __restrict__ h, const unsigned short* __restrict__ y1b,
    short* __restrict__ hb) {
    int n = blockIdx.x * 4 + (threadIdx.x >> 6);
    if (n >= N_NODES) return;
    int lane = threadIdx.x & 63;
    int beg = row_start[n], c = cnt[n];
    float acc = 0.f;
    int i = 0;
    for (; i + 1 < c; i += 2) {
        int s0 = col[beg + i], s1 = col[beg + i + 1];
        float w0 = dinv[s0], w1 = dinv[s1];
        float v0 = bf2f(y1b[(size_t)s0 * H1 + lane]);
        float v1 = bf2f(y1b[(size_t)s1 * H1 + lane]);
        acc += w0 * v0 + w1 * v1;
    }
    if (i < c) {
        int s0 = col[beg + i];
        acc += dinv[s0] * bf2f(y1b[(size_t)s0 * H1 + lane]);
    }
    size_t idx = (size_t)n * H1 + lane;
    float hf = h[idx] - dinv[n] * acc;
    hb[idx] = f2bf(fmaxf(hf, 0.f));
}

// ---------------- layer-2 MFMA GEMM: [out | y2b] = relu(h) @ [W0_2 | W1_2] ----------------
__global__ __launch_bounds__(256) void gemm2_mfma(
    const short* __restrict__ hb, const short* __restrict__ Bt2,
    const float* __restrict__ b2, float* __restrict__ out, short* __restrict__ y2b) {
    int lane = threadIdx.x & 63;
    int wave = threadIdx.x >> 6;
    int rowbase = blockIdx.x * 128 + wave * 32;
    int lr = lane & 15;
    int lk = (lane >> 4) * 8;

    short8 a[2][2];
#pragma unroll
    for (int mr = 0; mr < 2; ++mr) {
        int row = rowbase + mr * 16 + lr;
        int rc = (row < N_NODES) ? row : (N_NODES - 1);
        const short* p = hb + (size_t)rc * H1 + lk;
        a[mr][0] = *(const short8*)(p);
        a[mr][1] = *(const short8*)(p + 32);
    }

    f32x4 acc[2][4] = {};
#pragma unroll
    for (int cf = 0; cf < 4; ++cf) {
        const short* bp = Bt2 + (size_t)(cf * 16 + lr) * H1 + lk;
#pragma unroll
        for (int ks = 0; ks < 2; ++ks) {
            short8 b = *(const short8*)(bp + ks * 32);
            acc[0][cf] = __builtin_amdgcn_mfma_f32_16x16x32_bf16(a[0][ks], b, acc[0][cf], 0, 0, 0);
            acc[1][cf] = __builtin_amdgcn_mfma_f32_16x16x32_bf16(a[1][ks], b, acc[1][cf], 0, 0, 0);
        }
    }

    int srow = (lane >> 4) * 4;
#pragma unroll
    for (int mr = 0; mr < 2; ++mr) {
#pragma unroll
        for (int cf = 0; cf < 4; ++cf) {
            int colc = cf * 16 + lr;
            float bias = (colc < H2) ? b2[colc] : 0.f;
#pragma unroll
            for (int r = 0; r < 4; ++r) {
                int row = rowbase + mr * 16 + srow + r;
                if (row < N_NODES) {
                    float v = acc[mr][cf][r];
                    if (colc < H2) out[(size_t)row * H2 + colc] = v + bias;
                    else           y2b[(size_t)row * H2 + (colc - H2)] = f2bf(v);
                }
            }
        }
    }
}

// ------- gather layer 2: out[n] -= dinv[n] * sum(dinv[src]*y2[src]) -------
__global__ __launch_bounds__(256) void gather2_kernel(
    const int* __restrict__ row_start, const int* __restrict__ cnt,
    const int* __restrict__ col, const float* __restrict__ dinv,
    const unsigned short* __restrict__ y2b, float* __restrict__ out) {
    int wave = (blockIdx.x * 256 + threadIdx.x) >> 6;
    int lane = threadIdx.x & 63;
    int n = wave * 2 + (lane >> 5);
    if (n >= N_NODES) return;
    int c32 = lane & 31;
    int beg = row_start[n], c = cnt[n];
    float acc = 0.f;
    int i = 0;
    for (; i + 1 < c; i += 2) {
        int s0 = col[beg + i], s1 = col[beg + i + 1];
        float w0 = dinv[s0], w1 = dinv[s1];
        float v0 = bf2f(y2b[(size_t)s0 * H2 + c32]);
        float v1 = bf2f(y2b[(size_t)s1 * H2 + c32]);
        acc += w0 * v0 + w1 * v1;
    }
    if (i < c) {
        int s0 = col[beg + i];
        acc += dinv[s0] * bf2f(y2b[(size_t)s0 * H2 + c32]);
    }
    size_t idx = (size_t)n * H2 + c32;
    out[idx] = out[idx] - dinv[n] * acc;
}

extern "C" void kernel_launch(void* const* d_in, const int* in_sizes, int n_in,
                              void* d_out, int out_size, void* d_ws, size_t ws_size,
                              hipStream_t stream) {
    const float* verts = (const float*)d_in[0];
    const int*   edges = (const int*)  d_in[1];
    const float* W0_1  = (const float*)d_in[2];
    const float* W1_1  = (const float*)d_in[3];
    const float* b1    = (const float*)d_in[4];
    const float* W0_2  = (const float*)d_in[5];
    const float* W1_2  = (const float*)d_in[6];
    const float* b2    = (const float*)d_in[7];
    float* out = (float*)d_out;

    char* ws = (char*)d_ws;
    auto align256 = [](size_t x) { return (x + 255) & ~(size_t)255; };
    size_t o = 0;
    auto alloc = [&](size_t bytes) { size_t r = o; o = align256(o + bytes); return r; };

    int*   degi      = (int*)  (ws + alloc((size_t)N_NODES * 4));
    int*   cnt       = (int*)  (ws + alloc((size_t)N_NODES * 4));
    float* dinv      = (float*)(ws + alloc((size_t)N_NODES * 4));
    int*   excl      = (int*)  (ws + alloc((size_t)N_NODES * 4));
    int*   bsum      = (int*)  (ws + alloc((size_t)NBLK * 4));
    int*   row_start = (int*)  (ws + alloc((size_t)N_NODES * 4));
    int*   rank      = (int*)  (ws + alloc((size_t)N_EDGES * 4));
    int*   colarr    = (int*)  (ws + alloc((size_t)N_EDGES * 4));
    short* Bt1       = (short*)(ws + alloc((size_t)128 * IN_DIM * 2));
    short* Bt2       = (short*)(ws + alloc((size_t)64 * H1 * 2));
    float* h         = (float*)(ws + alloc((size_t)N_NODES * H1 * 4));
    short* y1b       = (short*)(ws + alloc((size_t)N_NODES * H1 * 2));
    short* hb        = (short*)(ws + alloc((size_t)N_NODES * H1 * 2));
    short* y2b       = (short*)(ws + alloc((size_t)N_NODES * H2 * 2));

    // degi and cnt are adjacent at the front: one memset covers both
    hipMemsetAsync(degi, 0, align256((size_t)N_NODES * 4) + (size_t)N_NODES * 4, stream);

    hist_kernel  <<<(N_EDGES + 255) / 256, 256, 0, stream>>>(edges, degi, cnt, rank);
    dinv_kernel  <<<NBLK, 256, 0, stream>>>(degi, dinv);
    scanA_kernel <<<NBLK, 256, 0, stream>>>(cnt, excl, bsum);
    scanB_kernel <<<1, 512, 0, stream>>>(bsum);
    scanC_kernel <<<NBLK, 256, 0, stream>>>(excl, bsum, row_start);
    fill_kernel  <<<(N_EDGES + 255) / 256, 256, 0, stream>>>(edges, rank, row_start, colarr);
    prep_w_kernel<<<(128 * IN_DIM + 64 * H1 + 255) / 256, 256, 0, stream>>>(W0_1, W1_1, W0_2, W1_2, Bt1, Bt2);

    gemm1_mfma    <<<(N_NODES + 127) / 128, 256, 0, stream>>>(verts, Bt1, b1, h, y1b);
    gather1_kernel<<<(N_NODES + 3) / 4, 256, 0, stream>>>(row_start, cnt, colarr, dinv, h, (const unsigned short*)y1b, hb);
    gemm2_mfma    <<<(N_NODES + 127) / 128, 256, 0, stream>>>(hb, Bt2, b2, out, y2b);
    gather2_kernel<<<(N_NODES + 7) / 8, 256, 0, stream>>>(row_start, cnt, colarr, dinv, (const unsigned short*)y2b, out);
}

// Round 5
// 305.990 us; speedup vs baseline: 2.5262x; 1.2699x over previous
//
#include <hip/hip_runtime.h>

#define N_NODES 100000
#define N_EDGES 1600000
#define IN_DIM  192
#define H1      64
#define H2      32
#define NBLK    ((N_NODES + 255) / 256)       // 391 scan blocks
#define NH      ((N_EDGES + 255) / 256)       // 6250 hist blocks
#define NG      ((N_NODES + 63) / 64)         // 1563 gemm1 blocks (64 rows each)
#define K1GRID  (NG * 5)                      // interleave 4 hist : 1 gemm

typedef __attribute__((ext_vector_type(8))) short short8;
typedef __attribute__((ext_vector_type(4))) float f32x4;

__device__ inline short f2bf(float f) {
    union { float f; unsigned u; } v; v.f = f;
    unsigned r = (v.u + 0x7FFFu + ((v.u >> 16) & 1u)) >> 16;
    return (short)r;
}
__device__ inline float bf2f(unsigned short s) {
    union { unsigned u; float f; } v; v.u = ((unsigned)s) << 16;
    return v.f;
}

// ---------------- weight prep: Bt1[128][192], Bt2[64][64], bf16, N-major ----------------
__global__ __launch_bounds__(256) void prep_w_kernel(
    const float* __restrict__ W0_1, const float* __restrict__ W1_1,
    const float* __restrict__ W0_2, const float* __restrict__ W1_2,
    short* __restrict__ Bt1, short* __restrict__ Bt2) {
    int idx = blockIdx.x * 256 + threadIdx.x;
    if (idx < 128 * IN_DIM) {
        int n = idx / IN_DIM, k = idx % IN_DIM;
        float v = (n < H1) ? W0_1[(size_t)k * H1 + n] : W1_1[(size_t)k * H1 + (n - H1)];
        Bt1[idx] = f2bf(v);
    } else {
        int j = idx - 128 * IN_DIM;
        if (j < 64 * H1) {
            int n = j / H1, k = j % H1;
            float v = (n < H2) ? W0_2[(size_t)k * H2 + n] : W1_2[(size_t)k * H2 + (n - H2)];
            Bt2[j] = f2bf(v);
        }
    }
}

// ---- K1 fused: hist (atomic/latency-bound) || gemm1 MFMA (compute-bound) ----
// blockIdx % 5 == 0 -> gemm1 tile (64 rows, 4 waves x 16 rows); else hist slice.
__global__ __launch_bounds__(256) void k1_fused(
    const int* __restrict__ edges, int* __restrict__ degi, int* __restrict__ cnt,
    int* __restrict__ rank,
    const float* __restrict__ verts, const short* __restrict__ Bt1,
    const float* __restrict__ b1, float* __restrict__ h, short* __restrict__ y1b) {
    int b = blockIdx.x;
    if (b % 5 != 0) {
        // ---------------- hist role ----------------
        int hidx = b - (b + 4) / 5;
        if (hidx >= NH) return;
        int e = hidx * 256 + threadIdx.x;
        if (e < N_EDGES) {
            int2 ed = ((const int2*)edges)[e];
            atomicAdd(&degi[ed.x], 1);
            rank[e] = atomicAdd(&cnt[ed.y], 1);
        }
        return;
    }
    // ---------------- gemm1 role: 16 rows/wave, N=128 (8 col-frags), K=192 ----------------
    int g = b / 5;
    int lane = threadIdx.x & 63;
    int wave = threadIdx.x >> 6;
    int rowbase = g * 64 + wave * 16;
    int lr = lane & 15;
    int lk = (lane >> 4) * 8;

    int row = rowbase + lr;
    int rc = (row < N_NODES) ? row : (N_NODES - 1);
    const float* p = verts + (size_t)rc * IN_DIM + lk;
    short8 a[6];
#pragma unroll
    for (int ks = 0; ks < 6; ++ks) {
        f32x4 u0 = *(const f32x4*)(p + ks * 32);
        f32x4 u1 = *(const f32x4*)(p + ks * 32 + 4);
        short8 t;
        t[0] = f2bf(u0[0]); t[1] = f2bf(u0[1]); t[2] = f2bf(u0[2]); t[3] = f2bf(u0[3]);
        t[4] = f2bf(u1[0]); t[5] = f2bf(u1[1]); t[6] = f2bf(u1[2]); t[7] = f2bf(u1[3]);
        a[ks] = t;
    }

    f32x4 acc[8] = {};
#pragma unroll
    for (int cf = 0; cf < 8; ++cf) {
        const short* bp = Bt1 + (size_t)(cf * 16 + lr) * IN_DIM + lk;
#pragma unroll
        for (int ks = 0; ks < 6; ++ks) {
            short8 bb = *(const short8*)(bp + ks * 32);
            acc[cf] = __builtin_amdgcn_mfma_f32_16x16x32_bf16(a[ks], bb, acc[cf], 0, 0, 0);
        }
    }

    int srow = (lane >> 4) * 4;
#pragma unroll
    for (int cf = 0; cf < 8; ++cf) {
        int colc = cf * 16 + lr;
        float bias = (colc < H1) ? b1[colc] : 0.f;
#pragma unroll
        for (int r = 0; r < 4; ++r) {
            int orow = rowbase + srow + r;
            if (orow < N_NODES) {
                float v = acc[cf][r];
                if (colc < H1) h[(size_t)orow * H1 + colc] = v + bias;
                else           y1b[(size_t)orow * H1 + (colc - H1)] = f2bf(v);
            }
        }
    }
}

// ---------------- scanA (+ fused dinv) ----------------
__global__ __launch_bounds__(256) void scanA_kernel(const int* __restrict__ cnt,
                                                    const int* __restrict__ degi,
                                                    float* __restrict__ dinv,
                                                    int* __restrict__ excl,
                                                    int* __restrict__ bsum) {
    __shared__ int s[256];
    int i = blockIdx.x * 256 + threadIdx.x;
    int v = (i < N_NODES) ? cnt[i] : 0;
    if (i < N_NODES) {
        int d = degi[i];
        dinv[i] = (d > 0) ? rsqrtf((float)d) : 0.f;
    }
    s[threadIdx.x] = v;
    __syncthreads();
    for (int off = 1; off < 256; off <<= 1) {
        int t = (threadIdx.x >= off) ? s[threadIdx.x - off] : 0;
        __syncthreads();
        s[threadIdx.x] += t;
        __syncthreads();
    }
    if (i < N_NODES) excl[i] = s[threadIdx.x] - v;
    if (threadIdx.x == 255) bsum[blockIdx.x] = s[255];
}

__global__ __launch_bounds__(512) void scanB_kernel(int* __restrict__ bsum) {
    __shared__ int s[512];
    int v = (threadIdx.x < NBLK) ? bsum[threadIdx.x] : 0;
    s[threadIdx.x] = v;
    __syncthreads();
    for (int off = 1; off < 512; off <<= 1) {
        int t = (threadIdx.x >= off) ? s[threadIdx.x - off] : 0;
        __syncthreads();
        s[threadIdx.x] += t;
        __syncthreads();
    }
    if (threadIdx.x < NBLK) bsum[threadIdx.x] = s[threadIdx.x] - v;
}

__global__ __launch_bounds__(256) void scanC_kernel(const int* __restrict__ excl,
                                                    const int* __restrict__ bsum,
                                                    int* __restrict__ row_start) {
    int i = blockIdx.x * 256 + threadIdx.x;
    if (i < N_NODES)
        row_start[i] = excl[i] + bsum[blockIdx.x];
    if (i == 0)
        row_start[N_NODES] = N_EDGES;   // sentinel so gathers use row_start[n+1]
}

// ------- CSR fill, atomic-free: col[row_start[dst] + rank[e]] = src -------
__global__ __launch_bounds__(256) void fill_kernel(const int* __restrict__ edges,
                                                   const int* __restrict__ rank,
                                                   const int* __restrict__ row_start,
                                                   int* __restrict__ col) {
    int e = blockIdx.x * blockDim.x + threadIdx.x;
    if (e < N_EDGES) {
        int2 ed = ((const int2*)edges)[e];
        col[row_start[ed.y] + rank[e]] = ed.x;
    }
}

// ------- gather layer 1 + fused relu/bf16: hb = bf16(relu(h - dinv*sum)) -------
// one wave per node; 4-way unrolled to break the dependent-load chain
__global__ __launch_bounds__(256) void gather1_kernel(
    const int* __restrict__ row_start, const int* __restrict__ col,
    const float* __restrict__ dinv, const float* __restrict__ h,
    const unsigned short* __restrict__ y1b, short* __restrict__ hb) {
    int n = blockIdx.x * 4 + (threadIdx.x >> 6);
    if (n >= N_NODES) return;
    int lane = threadIdx.x & 63;
    int beg = row_start[n], end = row_start[n + 1];
    float acc = 0.f;
    int i = beg;
    for (; i + 4 <= end; i += 4) {
        int s0 = col[i], s1 = col[i + 1], s2 = col[i + 2], s3 = col[i + 3];
        float w0 = dinv[s0], w1 = dinv[s1], w2 = dinv[s2], w3 = dinv[s3];
        float v0 = bf2f(y1b[(size_t)s0 * H1 + lane]);
        float v1 = bf2f(y1b[(size_t)s1 * H1 + lane]);
        float v2 = bf2f(y1b[(size_t)s2 * H1 + lane]);
        float v3 = bf2f(y1b[(size_t)s3 * H1 + lane]);
        acc += w0 * v0 + w1 * v1 + w2 * v2 + w3 * v3;
    }
    for (; i < end; ++i) {
        int s = col[i];
        acc += dinv[s] * bf2f(y1b[(size_t)s * H1 + lane]);
    }
    size_t idx = (size_t)n * H1 + lane;
    float hf = h[idx] - dinv[n] * acc;
    hb[idx] = f2bf(fmaxf(hf, 0.f));
}

// ---------------- layer-2 MFMA GEMM: [out | y2b] = relu(h) @ [W0_2 | W1_2] ----------------
__global__ __launch_bounds__(256) void gemm2_mfma(
    const short* __restrict__ hb, const short* __restrict__ Bt2,
    const float* __restrict__ b2, float* __restrict__ out, short* __restrict__ y2b) {
    int lane = threadIdx.x & 63;
    int wave = threadIdx.x >> 6;
    int rowbase = blockIdx.x * 128 + wave * 32;
    int lr = lane & 15;
    int lk = (lane >> 4) * 8;

    short8 a[2][2];
#pragma unroll
    for (int mr = 0; mr < 2; ++mr) {
        int row = rowbase + mr * 16 + lr;
        int rc = (row < N_NODES) ? row : (N_NODES - 1);
        const short* p = hb + (size_t)rc * H1 + lk;
        a[mr][0] = *(const short8*)(p);
        a[mr][1] = *(const short8*)(p + 32);
    }

    f32x4 acc[2][4] = {};
#pragma unroll
    for (int cf = 0; cf < 4; ++cf) {
        const short* bp = Bt2 + (size_t)(cf * 16 + lr) * H1 + lk;
#pragma unroll
        for (int ks = 0; ks < 2; ++ks) {
            short8 b = *(const short8*)(bp + ks * 32);
            acc[0][cf] = __builtin_amdgcn_mfma_f32_16x16x32_bf16(a[0][ks], b, acc[0][cf], 0, 0, 0);
            acc[1][cf] = __builtin_amdgcn_mfma_f32_16x16x32_bf16(a[1][ks], b, acc[1][cf], 0, 0, 0);
        }
    }

    int srow = (lane >> 4) * 4;
#pragma unroll
    for (int mr = 0; mr < 2; ++mr) {
#pragma unroll
        for (int cf = 0; cf < 4; ++cf) {
            int colc = cf * 16 + lr;
            float bias = (colc < H2) ? b2[colc] : 0.f;
#pragma unroll
            for (int r = 0; r < 4; ++r) {
                int row = rowbase + mr * 16 + srow + r;
                if (row < N_NODES) {
                    float v = acc[mr][cf][r];
                    if (colc < H2) out[(size_t)row * H2 + colc] = v + bias;
                    else           y2b[(size_t)row * H2 + (colc - H2)] = f2bf(v);
                }
            }
        }
    }
}

// ------- gather layer 2: out[n] -= dinv[n] * sum(dinv[src]*y2[src]) -------
// 2 nodes per wave; 4-way unrolled
__global__ __launch_bounds__(256) void gather2_kernel(
    const int* __restrict__ row_start, const int* __restrict__ col,
    const float* __restrict__ dinv, const unsigned short* __restrict__ y2b,
    float* __restrict__ out) {
    int wave = (blockIdx.x * 256 + threadIdx.x) >> 6;
    int lane = threadIdx.x & 63;
    int n = wave * 2 + (lane >> 5);
    if (n >= N_NODES) return;
    int c32 = lane & 31;
    int beg = row_start[n], end = row_start[n + 1];
    float acc = 0.f;
    int i = beg;
    for (; i + 4 <= end; i += 4) {
        int s0 = col[i], s1 = col[i + 1], s2 = col[i + 2], s3 = col[i + 3];
        float w0 = dinv[s0], w1 = dinv[s1], w2 = dinv[s2], w3 = dinv[s3];
        float v0 = bf2f(y2b[(size_t)s0 * H2 + c32]);
        float v1 = bf2f(y2b[(size_t)s1 * H2 + c32]);
        float v2 = bf2f(y2b[(size_t)s2 * H2 + c32]);
        float v3 = bf2f(y2b[(size_t)s3 * H2 + c32]);
        acc += w0 * v0 + w1 * v1 + w2 * v2 + w3 * v3;
    }
    for (; i < end; ++i) {
        int s = col[i];
        acc += dinv[s] * bf2f(y2b[(size_t)s * H2 + c32]);
    }
    size_t idx = (size_t)n * H2 + c32;
    out[idx] = out[idx] - dinv[n] * acc;
}

extern "C" void kernel_launch(void* const* d_in, const int* in_sizes, int n_in,
                              void* d_out, int out_size, void* d_ws, size_t ws_size,
                              hipStream_t stream) {
    const float* verts = (const float*)d_in[0];
    const int*   edges = (const int*)  d_in[1];
    const float* W0_1  = (const float*)d_in[2];
    const float* W1_1  = (const float*)d_in[3];
    const float* b1    = (const float*)d_in[4];
    const float* W0_2  = (const float*)d_in[5];
    const float* W1_2  = (const float*)d_in[6];
    const float* b2    = (const float*)d_in[7];
    float* out = (float*)d_out;

    char* ws = (char*)d_ws;
    auto align256 = [](size_t x) { return (x + 255) & ~(size_t)255; };
    size_t o = 0;
    auto alloc = [&](size_t bytes) { size_t r = o; o = align256(o + bytes); return r; };

    int*   degi      = (int*)  (ws + alloc((size_t)N_NODES * 4));
    int*   cnt       = (int*)  (ws + alloc((size_t)N_NODES * 4));
    float* dinv      = (float*)(ws + alloc((size_t)N_NODES * 4));
    int*   excl      = (int*)  (ws + alloc((size_t)N_NODES * 4));
    int*   bsum      = (int*)  (ws + alloc((size_t)NBLK * 4));
    int*   row_start = (int*)  (ws + alloc((size_t)(N_NODES + 1) * 4));
    int*   rank      = (int*)  (ws + alloc((size_t)N_EDGES * 4));
    int*   colarr    = (int*)  (ws + alloc((size_t)N_EDGES * 4));
    short* Bt1       = (short*)(ws + alloc((size_t)128 * IN_DIM * 2));
    short* Bt2       = (short*)(ws + alloc((size_t)64 * H1 * 2));
    float* h         = (float*)(ws + alloc((size_t)N_NODES * H1 * 4));
    short* y1b       = (short*)(ws + alloc((size_t)N_NODES * H1 * 2));
    short* hb        = (short*)(ws + alloc((size_t)N_NODES * H1 * 2));
    short* y2b       = (short*)(ws + alloc((size_t)N_NODES * H2 * 2));

    // degi and cnt are adjacent at the front: one memset covers both
    hipMemsetAsync(degi, 0, align256((size_t)N_NODES * 4) + (size_t)N_NODES * 4, stream);

    prep_w_kernel<<<(128 * IN_DIM + 64 * H1 + 255) / 256, 256, 0, stream>>>(W0_1, W1_1, W0_2, W1_2, Bt1, Bt2);
    k1_fused     <<<K1GRID, 256, 0, stream>>>(edges, degi, cnt, rank, verts, Bt1, b1, h, y1b);
    scanA_kernel <<<NBLK, 256, 0, stream>>>(cnt, degi, dinv, excl, bsum);
    scanB_kernel <<<1, 512, 0, stream>>>(bsum);
    scanC_kernel <<<NBLK, 256, 0, stream>>>(excl, bsum, row_start);
    fill_kernel  <<<(N_EDGES + 255) / 256, 256, 0, stream>>>(edges, rank, row_start, colarr);

    gather1_kernel<<<(N_NODES + 3) / 4, 256, 0, stream>>>(row_start, colarr, dinv, h, (const unsigned short*)y1b, hb);
    gemm2_mfma    <<<(N_NODES + 127) / 128, 256, 0, stream>>>(hb, Bt2, b2, out, y2b);
    gather2_kernel<<<(N_NODES + 7) / 8, 256, 0, stream>>>(row_start, colarr, dinv, (const unsigned short*)y2b, out);
}